// Round 4
// baseline (305.056 us; speedup 1.0000x reference)
//
#include <hip/hip_runtime.h>
#include <stdint.h>

#define BB 512
#define TT 1000
#define CC 64
#define HH 128
#define TDA_F 150
#define NCLS 4
#define EPSV 1e-5f
#define NSEG 8
#define SEGLEN 125   // TT / NSEG
#define WARM 51      // uncounted warm-up; SEGLEN+WARM = 176 = 11 tiles of 16

typedef _Float16 half8 __attribute__((ext_vector_type(8)));
typedef float floatx4 __attribute__((ext_vector_type(4)));

// Split 8 fp32 values into fp16 hi + lo halves (hi = RTN cvt, lo = residual).
// (hi+lo) carries ~22 mantissa bits; 3-product MFMA error ~2^-21 relative.
__device__ __forceinline__ void split8(const float* v, half8& hi, half8& lo) {
#pragma unroll
  for (int i = 0; i < 8; ++i) {
    _Float16 h = (_Float16)v[i];
    hi[i] = h;
    lo[i] = (_Float16)(v[i] - (float)h);
  }
}

// ---------------------------------------------------------------------------
// Fused current-GEMM (split-fp16 MFMA) + LIF scan. Grid 512b x 8seg x 2hh,
// single-wave blocks; wave owns 64 h (4 h-tiles), 4 waves/SIMD (64 VGPR +
// 64 AGPR weight frags = 128 unified regs).
//
// R8: INSTRUCTION DIET (R7 showed occupancy 2->4 waves left time at 77us;
// VALU-busy cycles == demand exactly, 48% of wall is no-issue stall).
// (a) Transposed LDS curT[64 h][20 t] (stride 80B, 16B-aligned rows): the
//     MFMA D regs are 4 consecutive t for fixed h -> ONE ds_write_b128 per
//     h-tile (4/tile vs 16 b32); LIF side reads 4x ds_read_b128. Both
//     patterns split into 8-lane phases covering all 32 banks (dword index
//     = 20h+4t ≡ 4*((5h+t) mod 8) mod 32) -> conflict-free at the b128
//     floor. 32 -> 8 LDS instrs/tile.
// (b) Tile-mode split: act is tile-uniform except ONE boundary tile per seg
//     (seg0: tile 7 hits hi=125; seg>0: tile 3 spans warm/active). WARM
//     tiles skip cnt entirely (cnt+=0 identity), ACTIVE tiles drop the
//     act mask -> kills ~60 SALU/VALU issue slots per tile on 10/11 tiles.
// Arithmetic is bit-identical to R7 (same FMA order, same LIF order).
// ---------------------------------------------------------------------------

#define MFMA16(A, B, ACC) __builtin_amdgcn_mfma_f32_16x16x32_f16(A, B, ACC, 0, 0, 0)

// One 16t x 64h tile: split A, 24 MFMA, 4 b128 stores to curT.
#define TILE_GEMM(PREF)                                                       \
  {                                                                           \
    float4 c0 = p0, c1 = p1, c2 = p2, c3 = p3;                                \
    if (PREF) {                                                               \
      ab += 16 * CC;                                                          \
      p0 = *(const float4*)(ab);                                              \
      p1 = *(const float4*)(ab + 4);                                          \
      p2 = *(const float4*)(ab + 32);                                         \
      p3 = *(const float4*)(ab + 36);                                         \
    }                                                                         \
    float av0[8] = {c0.x, c0.y, c0.z, c0.w, c1.x, c1.y, c1.z, c1.w};          \
    float av1[8] = {c2.x, c2.y, c2.z, c2.w, c3.x, c3.y, c3.z, c3.w};          \
    half8 ah0, al0, ah1, al1;                                                 \
    split8(av0, ah0, al0);                                                    \
    split8(av1, ah1, al1);                                                    \
    _Pragma("unroll")                                                         \
    for (int ht = 0; ht < 4; ++ht) {                                          \
      floatx4 acc = {bv[ht], bv[ht], bv[ht], bv[ht]};                         \
      acc = MFMA16(al0, bh[ht][0], acc);                                      \
      acc = MFMA16(ah0, bl[ht][0], acc);                                      \
      acc = MFMA16(ah0, bh[ht][0], acc);                                      \
      acc = MFMA16(al1, bh[ht][1], acc);                                      \
      acc = MFMA16(ah1, bl[ht][1], acc);                                      \
      acc = MFMA16(ah1, bh[ht][1], acc);                                      \
      /* D: col = lane&15 = h-in-tile, row = q*4+r = t -> 4 consecutive t */  \
      *(floatx4*)&curT[ht * 16 + m][q * 4] = acc;                             \
    }                                                                         \
  }

// Pull this tile's 16 currents for h = lane into registers (4 x b128).
#define LIF_LOAD()                                                            \
  float cu[16];                                                               \
  {                                                                           \
    _Pragma("unroll")                                                         \
    for (int j = 0; j < 4; ++j) {                                             \
      floatx4 rr = *(const floatx4*)&curT[lane][j * 4];                       \
      cu[j * 4 + 0] = rr[0]; cu[j * 4 + 1] = rr[1];                           \
      cu[j * 4 + 2] = rr[2]; cu[j * 4 + 3] = rr[3];                           \
    }                                                                         \
  }

#define LIF_ACT()                                                             \
  {                                                                           \
    LIF_LOAD();                                                               \
    _Pragma("unroll")                                                         \
    for (int s = 0; s < 16; ++s) {                                            \
      mem = fmaf(0.9f, mem, cu[s]);                                           \
      const bool sp = (mem >= 1.0f);                                          \
      cnt += sp ? 1.0f : 0.0f;                                                \
      mem = sp ? 0.0f : mem;                                                  \
    }                                                                         \
  }

#define LIF_WARM()                                                            \
  {                                                                           \
    LIF_LOAD();                                                               \
    _Pragma("unroll")                                                         \
    for (int s = 0; s < 16; ++s) {                                            \
      mem = fmaf(0.9f, mem, cu[s]);                                           \
      const bool sp = (mem >= 1.0f);                                          \
      mem = sp ? 0.0f : mem;                                                  \
    }                                                                         \
  }

#define LIF_MIX(TB)                                                           \
  {                                                                           \
    LIF_LOAD();                                                               \
    const int tb_ = (TB);                                                     \
    _Pragma("unroll")                                                         \
    for (int s = 0; s < 16; ++s) {                                            \
      const int t = tb_ + s;                                                  \
      const bool act = (t >= lo) && (t < hi); /* wave-uniform */              \
      mem = fmaf(0.9f, mem, cu[s]);                                           \
      const bool sp = (mem >= 1.0f);                                          \
      cnt += (act && sp) ? 1.0f : 0.0f;                                       \
      mem = sp ? 0.0f : mem;                                                  \
    }                                                                         \
  }

__global__ __launch_bounds__(64, 4) void snn_scan(
    const float* __restrict__ kin, const float* __restrict__ Wfc,
    const float* __restrict__ bfc, float* __restrict__ part)
{
  const int lane = threadIdx.x;
  const int q = lane >> 4;      // quad 0..3
  const int m = lane & 15;      // row-in-tile / col-in-tile index
  const int idx = blockIdx.x;
  const int hh = idx & 1;       // h-half: this wave owns h = hh*64 .. +63
  const int seg = (idx >> 1) & 7;
  const int b = idx >> 4;

  const int t0 = (seg == 0) ? 0 : SEGLEN * seg - WARM;
  const int lo = SEGLEN * seg;
  const int hi = lo + SEGLEN;

  // B fragments: B[n=m][k=q*8+j], n = hh*64 + ht*16 + m over 4 h-tiles,
  // k split in two 32-wide halves. 16 half8 frags = 64 regs (AGPR).
  half8 bh[4][2], bl[4][2];
  float bv[4];
#pragma unroll
  for (int ht = 0; ht < 4; ++ht) {
    const int h = hh * 64 + ht * 16 + m;
    bv[ht] = bfc[h];
#pragma unroll
    for (int kh = 0; kh < 2; ++kh) {
      const float* wp = Wfc + h * CC + kh * 32 + q * 8;
      float av[8];
      float4 w0 = *(const float4*)(wp);
      float4 w1 = *(const float4*)(wp + 4);
      av[0] = w0.x; av[1] = w0.y; av[2] = w0.z; av[3] = w0.w;
      av[4] = w1.x; av[5] = w1.y; av[6] = w1.z; av[7] = w1.w;
      split8(av, bh[ht][kh], bl[ht][kh]);
    }
  }

  // Transposed current tile: [h-local][t], row stride 20 floats = 80 B.
  __shared__ __align__(16) float curT[64][20];

  // A pointer: lane reads rows t = t_base + m, cols q*8.. (two k-halves).
  const float* ab = kin + ((size_t)b * TT + (t0 + m)) * CC + q * 8;

  float4 p0 = *(const float4*)(ab);
  float4 p1 = *(const float4*)(ab + 4);
  float4 p2 = *(const float4*)(ab + 32);
  float4 p3 = *(const float4*)(ab + 36);

  float mem = 0.f, cnt = 0.f;

  if (seg == 0) {
    // 8 tiles: 0..6 fully active, 7 mixed (t 112..127 vs hi=125).
#pragma unroll 1
    for (int k = 0; k < 7; ++k) { TILE_GEMM(true); LIF_ACT(); }
    TILE_GEMM(false); LIF_MIX(112);
  } else {
    // 11 tiles: 0..2 warm, 3 mixed (t0+48..63 vs lo=t0+51), 4..10 active.
#pragma unroll 1
    for (int k = 0; k < 3; ++k) { TILE_GEMM(true); LIF_WARM(); }
    TILE_GEMM(true); LIF_MIX(t0 + 48);
#pragma unroll 1
    for (int k = 0; k < 6; ++k) { TILE_GEMM(true); LIF_ACT(); }
    TILE_GEMM(false); LIF_ACT();
  }

  part[((size_t)(seg * BB + b)) * HH + hh * 64 + lane] = cnt;
}

// ---------------------------------------------------------------------------
// Fused head: partial-count reduce + counts output + tda_net
// (150->64 relu ->64 relu) + fc1 (192->128). No atomics.
// ---------------------------------------------------------------------------
__global__ __launch_bounds__(HH) void fused_head(
    const float* __restrict__ part, const float* __restrict__ tda,
    const float* __restrict__ W1, const float* __restrict__ b1,
    const float* __restrict__ W2, const float* __restrict__ b2,
    const float* __restrict__ Wc1, const float* __restrict__ bc1,
    float* __restrict__ counts_out, float* __restrict__ hbuf)
{
  const int b = blockIdx.x, j = threadIdx.x;
  __shared__ float x[TDA_F];
  __shared__ float h1[64];
  __shared__ float f[HH + 64];

  float c = 0.0f;
#pragma unroll
  for (int s = 0; s < NSEG; ++s) c += part[((size_t)(s * BB + b)) * HH + j];
  counts_out[b * HH + j] = c;
  f[j] = c * (1.0f / TT);
  for (int i = j; i < TDA_F; i += HH) x[i] = tda[b * TDA_F + i];
  __syncthreads();
  if (j < 64) {
    float acc = b1[j];
    const float* wr = W1 + j * TDA_F;
#pragma unroll 5
    for (int i = 0; i < TDA_F; ++i) acc = fmaf(x[i], wr[i], acc);
    h1[j] = fmaxf(acc, 0.0f);
  }
  __syncthreads();
  if (j < 64) {
    float acc = b2[j];
    const float* wr = W2 + j * 64;
#pragma unroll
    for (int i = 0; i < 64; ++i) acc = fmaf(h1[i], wr[i], acc);
    f[HH + j] = fmaxf(acc, 0.0f);
  }
  __syncthreads();
  float acc = bc1[j];
  const float* wr = Wc1 + j * (HH + 64);
#pragma unroll 4
  for (int i = 0; i < HH + 64; ++i) acc = fmaf(f[i], wr[i], acc);
  hbuf[b * HH + j] = acc;
}

// ---------------------------------------------------------------------------
// BN batch stats: 128 blocks (one per column) x 256 threads; per-thread 2
// strided loads, shuffle reduce. Reduction-order perturbs mean/var ~1e-7.
// ---------------------------------------------------------------------------
__global__ __launch_bounds__(256) void bn_stats(
    const float* __restrict__ hbuf, float* __restrict__ stats /* [2*128] */)
{
  const int j = blockIdx.x;    // column
  const int t = threadIdx.x;   // 0..255
  float v0 = hbuf[(size_t)t * HH + j];
  float v1 = hbuf[(size_t)(t + 256) * HH + j];
  float s = v0 + v1;
  float qd = v0 * v0 + v1 * v1;
#pragma unroll
  for (int o = 32; o >= 1; o >>= 1) {
    s += __shfl_down(s, o);
    qd += __shfl_down(qd, o);
  }
  __shared__ float ps[4], pq[4];
  if ((t & 63) == 0) { ps[t >> 6] = s; pq[t >> 6] = qd; }
  __syncthreads();
  if (t == 0) {
    const float S = (ps[0] + ps[1]) + (ps[2] + ps[3]);
    const float Q = (pq[0] + pq[1]) + (pq[2] + pq[3]);
    const float mean = S * (1.0f / BB);
    const float var = Q * (1.0f / BB) - mean * mean;
    stats[j] = mean;
    stats[HH + j] = rsqrtf(var + EPSV);
  }
}

// ---------------------------------------------------------------------------
// BN apply + relu + 128->4 GEMM.
// ---------------------------------------------------------------------------
__global__ __launch_bounds__(HH) void classifier2(
    const float* __restrict__ hbuf, const float* __restrict__ stats,
    const float* __restrict__ gamma, const float* __restrict__ beta,
    const float* __restrict__ Wc2, const float* __restrict__ bc2,
    float* __restrict__ out)
{
  const int b = blockIdx.x, j = threadIdx.x;
  float hn = (hbuf[b * HH + j] - stats[j]) * stats[HH + j] * gamma[j] + beta[j];
  hn = fmaxf(hn, 0.0f);

  __shared__ float red[NCLS][HH];
#pragma unroll
  for (int k = 0; k < NCLS; ++k) red[k][j] = hn * Wc2[k * HH + j];
  __syncthreads();
  for (int off = HH / 2; off >= 1; off >>= 1) {
    if (j < off) {
#pragma unroll
      for (int k = 0; k < NCLS; ++k) red[k][j] += red[k][j + off];
    }
    __syncthreads();
  }
  if (j < NCLS) out[b * NCLS + j] = red[j][0] + bc2[j];
}

// ---------------------------------------------------------------------------
extern "C" void kernel_launch(void* const* d_in, const int* in_sizes, int n_in,
                              void* d_out, int out_size, void* d_ws, size_t ws_size,
                              hipStream_t stream)
{
  const float* kin  = (const float*)d_in[0];   // [512,1000,64]
  const float* tda  = (const float*)d_in[1];   // [512,150]
  const float* Wfc  = (const float*)d_in[2];   // [128,64]
  const float* bfc  = (const float*)d_in[3];   // [128]
  const float* Wt1  = (const float*)d_in[4];   // [64,150]
  const float* bt1  = (const float*)d_in[5];   // [64]
  const float* Wt2  = (const float*)d_in[6];   // [64,64]
  const float* bt2  = (const float*)d_in[7];   // [64]
  const float* Wc1  = (const float*)d_in[8];   // [128,192]
  const float* bc1  = (const float*)d_in[9];   // [128]
  const float* gam  = (const float*)d_in[10];  // [128]
  const float* bet  = (const float*)d_in[11];  // [128]
  const float* Wc2  = (const float*)d_in[12];  // [4,128]
  const float* bc2  = (const float*)d_in[13];  // [4]

  float* out    = (float*)d_out;        // output 0: [512,4]
  float* counts = out + BB * NCLS;      // output 1: [512,128]

  float* part  = (float*)d_ws;               // [8][512][128]  (2 MB)
  float* hbuf  = part + NSEG * BB * HH;      // [512,128]
  float* stats = hbuf + BB * HH;             // [256]

  snn_scan<<<BB * NSEG * 2, 64, 0, stream>>>(kin, Wfc, bfc, part);
  fused_head<<<BB, HH, 0, stream>>>(part, tda, Wt1, bt1, Wt2, bt2,
                                    Wc1, bc1, counts, hbuf);
  bn_stats<<<HH, 256, 0, stream>>>(hbuf, stats);
  classifier2<<<BB, HH, 0, stream>>>(hbuf, stats, gam, bet, Wc2, bc2, out);
}